// Round 7
// baseline (98.236 us; speedup 1.0000x reference)
//
#include <hip/hip_runtime.h>
#include <math.h>

// Problem constants (match reference)
#define BB   16
#define CC   64
#define LL   512
#define LP   16
#define DM   1024
#define NP   64
#define PRD  256   // period = L/2
#define HEAD 128   // PRD/2
#define NV   256   // L - PRD

typedef float f32x4 __attribute__((ext_vector_type(4)));

// workspace layout (in floats); all offsets 16B-aligned
#define OFF_MEANP 0                    // 8192
#define OFF_WSF   8192                 // 16*256 folded seasonal weights
#define OFF_WRS   (8192 + 4096)        // 16 resid weight sums

// ---------------------------------------------------------------------------
// Kernel 1: blocks 0..31 = per-(b,l) channel stats; block 32 = weight folding.
// ---------------------------------------------------------------------------
__global__ __launch_bounds__(256) void statsprep_kernel(
    const float* __restrict__ dx, const float* __restrict__ w_s,
    const float* __restrict__ w_r, float* __restrict__ ws)
{
    const int tid = threadIdx.x, bid = blockIdx.x;
    if (bid < 32) {
        int id = bid * 256 + tid;            // 0..8191
        int b = id >> 9, l = id & 511;
        const float* p = dx + (size_t)b * CC * LL + l;
        float s = 0.f, sq = 0.f;
#pragma unroll 8
        for (int c = 0; c < CC; ++c) {
            float v = p[(size_t)c * LL];
            s += v; sq += v * v;
        }
        float mean = s * (1.0f / CC);
        float var  = (sq - (float)CC * mean * mean) * (1.0f / (CC - 1));
        ws[OFF_MEANP + id] = mean / sqrtf(var);
    } else {
        // fold seasonal weights: wsf[g][m] = w_s[g][m] + w_s[g][m+256]
#pragma unroll
        for (int idx = tid; idx < 16 * PRD; idx += 256) {
            int g = idx >> 8, m = idx & 255;
            ws[OFF_WSF + idx] = w_s[g * LL + m] + w_s[g * LL + PRD + m];
        }
        // resid weight sums: wrs[g] = sum w_r[g][128:384]
        int g = tid >> 4, ln = tid & 15;
        float s = 0.f;
        for (int k = ln; k < PRD; k += 16) s += w_r[g * LL + HEAD + k];
#pragma unroll
        for (int m = 8; m; m >>= 1) s += __shfl_xor(s, m, 16);
        if (ln == 0) ws[OFF_WRS + g] = s;
    }
}

// ---------------------------------------------------------------------------
// Kernel 2 (fused): one block per (b,c). Transform -> scan decompose ->
// 48 features (LDS) -> per-thread 4-row matvec vs w_g (L2-hot, 192KB) ->
// stream 64 broadcast copies (256 KB) straight to out. No resbuf round-trip.
// ---------------------------------------------------------------------------
__global__ __launch_bounds__(256, 4) void fused_kernel(
    const float* __restrict__ dx,    const float* __restrict__ gamma,
    const float* __restrict__ beta,  const float* __restrict__ w_t,
    const float* __restrict__ b_t,   const float* __restrict__ b_s,
    const float* __restrict__ b_r,   const float* __restrict__ w_g,
    const float* __restrict__ b_g,   const float* __restrict__ ws,
    float* __restrict__ out)
{
    __shared__ __align__(16) float xs[LL];
    __shared__ __align__(16) float pps[LL/2 + 1];
    __shared__ __align__(16) float tvs[NV];
    __shared__ __align__(16) float pas[PRD];
    __shared__ __align__(16) float feats[48];
    __shared__ float wsum[4];
    __shared__ float wred[4];

    const int tid  = threadIdx.x;
    const int lane = tid & 63;
    const int wv   = tid >> 6;
    const int bc   = blockIdx.x;
    const int b    = bc >> 6;

    // transform (float2): x = gamma*(dx - meanp) + beta
    const size_t base = (size_t)bc * LL;
    float2 xv = ((const float2*)(dx    + base))[tid];
    float2 gv = ((const float2*)(gamma + base))[tid];
    float2 bv = ((const float2*)(beta  + base))[tid];
    float2 mv = ((const float2*)(ws + OFF_MEANP + (size_t)b * LL))[tid];
    float2 xp;
    xp.x = gv.x * (xv.x - mv.x) + bv.x;
    xp.y = gv.y * (xv.y - mv.y) + bv.y;
    ((float2*)xs)[tid] = xp;

    // inclusive scan of pair-sums (256 pairs)
    float v = xp.x + xp.y;
#pragma unroll
    for (int d = 1; d < 64; d <<= 1) {
        float t = __shfl_up(v, d, 64);
        if (lane >= d) v += t;
    }
    if (lane == 63) wsum[wv] = v;
    __syncthreads();
    float off = 0.f;
    for (int w = 0; w < wv; ++w) off += wsum[w];
    pps[tid + 1] = v + off;
    if (tid == 0) pps[0] = 0.f;
    __syncthreads();

    // trend via prefix sums
    const int i  = tid;
    const int k2 = i + 257;
    const float Pi = pps[i  >> 1] + ((i  & 1) ? xs[i  & ~1] : 0.f);
    const float Pk = pps[k2 >> 1] + ((k2 & 1) ? xs[k2 & ~1] : 0.f);
    const float tv = (Pk - Pi - 0.5f * (xs[i] + xs[i + 256])) * (1.0f / 256.0f);
    tvs[i] = tv;
    const float dv = xs[HEAD + i] - tv;

    // mdv = mean(dv)
    float r = dv;
#pragma unroll
    for (int m = 32; m; m >>= 1) r += __shfl_xor(r, m, 64);
    if (lane == 0) wred[wv] = r;
    __syncthreads();
    const float mdv = (wred[0] + wred[1] + wred[2] + wred[3]) * (1.0f / 256.0f);

    pas[(i + 128) & 255] = dv - mdv;
    __syncthreads();

    // feature dots with folded weights (8 float4 loads/thread)
    {
        const int g  = tid >> 4;
        const int ln = tid & 15;
        const f32x4* wt4  = (const f32x4*)(w_t + g * LL + HEAD);
        const f32x4* wsf4 = (const f32x4*)(ws + OFF_WSF + g * PRD);
        const f32x4* tv4  = (const f32x4*)tvs;
        const f32x4* pa4  = (const f32x4*)pas;
        float at = 0.f, as = 0.f;
#pragma unroll
        for (int q = 0; q < 4; ++q) {
            const int m = ln * 4 + q;
            f32x4 t = tv4[m], p = pa4[m];
            f32x4 a = wt4[m], sfw = wsf4[m];
            at += t.x * a.x + t.y * a.y + t.z * a.z + t.w * a.w;
            as += p.x * sfw.x + p.y * sfw.y + p.z * sfw.z + p.w * sfw.w;
        }
#pragma unroll
        for (int msk = 8; msk; msk >>= 1) {
            at += __shfl_xor(at, msk, 64);
            as += __shfl_xor(as, msk, 64);
        }
        if (ln == 0) {
            feats[g]      = at + b_t[g];
            feats[16 + g] = as + b_s[g];
            feats[32 + g] = mdv * ws[OFF_WRS + g] + b_r[g];
        }
    }
    __syncthreads();

    // ---- per-thread matvec: 4 consecutive d rows of w_g (48 floats each).
    // w_g is 192 KB -> L2-hot per XCD after the first blocks touch it.
    f32x4 f[12];
    const f32x4* fr4 = (const f32x4*)feats;
#pragma unroll
    for (int j = 0; j < 12; ++j) f[j] = fr4[j];

    const int d0 = tid * 4;
    const f32x4 bg = ((const f32x4*)b_g)[tid];
    float a[4];
#pragma unroll
    for (int row = 0; row < 4; ++row) {
        const f32x4* wg4 = (const f32x4*)(w_g + (size_t)(d0 + row) * 48);
        float acc = 0.f;
#pragma unroll
        for (int j = 0; j < 12; ++j) {
            f32x4 w = wg4[j];
            acc += f[j].x * w.x + f[j].y * w.y + f[j].z * w.z + f[j].w * w.w;
        }
        a[row] = acc;
    }
    f32x4 res;
    res.x = a[0] + bg.x; res.y = a[1] + bg.y;
    res.z = a[2] + bg.z; res.w = a[3] + bg.w;

    // ---- stream 64 identical patch rows (256 KB per block), plain stores
    f32x4* op = (f32x4*)out + (size_t)bc * (NP * DM / 4) + tid;
#pragma unroll
    for (int n = 0; n < NP; ++n)
        op[(size_t)n * (DM / 4)] = res;
}

// ---------------------------------------------------------------------------
extern "C" void kernel_launch(void* const* d_in, const int* in_sizes, int n_in,
                              void* d_out, int out_size, void* d_ws, size_t ws_size,
                              hipStream_t stream) {
    const float* dx    = (const float*)d_in[0];
    const float* gamma = (const float*)d_in[1];
    const float* beta  = (const float*)d_in[2];
    const float* w_t   = (const float*)d_in[3];
    const float* b_t   = (const float*)d_in[4];
    const float* w_s   = (const float*)d_in[5];
    const float* b_s   = (const float*)d_in[6];
    const float* w_r   = (const float*)d_in[7];
    const float* b_r   = (const float*)d_in[8];
    const float* w_g   = (const float*)d_in[9];
    const float* b_g   = (const float*)d_in[10];
    float* out = (float*)d_out;
    float* ws  = (float*)d_ws;

    statsprep_kernel<<<33, 256, 0, stream>>>(dx, w_s, w_r, ws);
    fused_kernel<<<BB * CC, 256, 0, stream>>>(
        dx, gamma, beta, w_t, b_t, b_s, b_r, w_g, b_g, ws, out);
}